// Round 3
// baseline (223.242 us; speedup 1.0000x reference)
//
#include <hip/hip_runtime.h>
#include <math.h>

// PAM module on MFMA, v3: B=4, C=256, H=W=64 -> N=4096, CK=32.
// k0a: pack W -> bf16 [320][256] + bias[320]
// k0b: transpose x -> xT[b][n][c] bf16
// k1 : MFMA QKV -> Q[b][n][32], K[b][m][32] (bf16), Vc[b][c][m] (bf16)
// k2 : MFMA flash attention, 32 rows/wave, G=2 KV split, no K/V LDS staging
//      (K/V L2-resident per XCD; L1 dedups across the block's 4 waves),
//      O^T accumulation -> bf16 partials Op[g][b][c][n] + (Mp,Lp)[g][b][n]
// k3 : combine partials + gamma*O + x  (fused epilogue)

#define BB 4
#define CC 256
#define NN 4096
#define CKK 32
#define G2 2

typedef __attribute__((ext_vector_type(4))) float f32x4;
typedef __attribute__((ext_vector_type(8))) short short8;
typedef __attribute__((ext_vector_type(4))) short short4v;

static __device__ __forceinline__ ushort f2bf(float f) {
    union { float f; unsigned u; } v; v.f = f;
    unsigned r = v.u + 0x7FFFu + ((v.u >> 16) & 1u);
    return (ushort)(r >> 16);
}
static __device__ __forceinline__ float bf2f(ushort h) {
    union { unsigned u; float f; } v; v.u = ((unsigned)h) << 16;
    return v.f;
}

// ---------------- k0a: pack weights + biases to bf16 ----------------
__global__ __launch_bounds__(256) void pack_w_kernel(
    const float* __restrict__ Wq, const float* __restrict__ bq,
    const float* __restrict__ Wk, const float* __restrict__ bk,
    const float* __restrict__ Wv, const float* __restrict__ bv,
    ushort* __restrict__ Wb, float* __restrict__ bias)
{
    const int o = blockIdx.x;      // 0..319
    const int c = threadIdx.x;     // 0..255
    const float* src; float bsc;
    if (o < 32)      { src = Wq + o * CC;        bsc = bq[o]; }
    else if (o < 64) { src = Wk + (o - 32) * CC; bsc = bk[o - 32]; }
    else             { src = Wv + (o - 64) * CC; bsc = bv[o - 64]; }
    Wb[o * CC + c] = f2bf(src[c]);
    if (c == 0) bias[o] = bsc;
}

// ---------------- k0b: x[b][c][n] fp32 -> xT[b][n][c] bf16 ----------------
__global__ __launch_bounds__(256) void xpose_kernel(
    const float* __restrict__ x, ushort* __restrict__ xT)
{
    __shared__ float t[32][33];
    const int b = blockIdx.z, c0 = blockIdx.y * 32, n0 = blockIdx.x * 32;
    const int tid = threadIdx.x;
    #pragma unroll
    for (int i = 0; i < 4; ++i) {
        int idx = tid + i * 256, rr = idx >> 5, nn = idx & 31;
        t[rr][nn] = x[((size_t)b * CC + c0 + rr) * NN + n0 + nn];
    }
    __syncthreads();
    #pragma unroll
    for (int i = 0; i < 4; ++i) {
        int idx = tid + i * 256, rr = idx >> 5, cc = idx & 31;
        xT[((size_t)b * NN + n0 + rr) * CC + c0 + cc] = f2bf(t[cc][rr]);
    }
}

// ---------------- k1: QKV projections via MFMA ----------------
__global__ __launch_bounds__(256) void qkv_mfma_kernel(
    const ushort* __restrict__ Wb, const float* __restrict__ bias,
    const ushort* __restrict__ xT,
    ushort* __restrict__ Q, ushort* __restrict__ Kt, ushort* __restrict__ V)
{
    const int b = blockIdx.y, n0 = blockIdx.x * 64;
    const int tid = threadIdx.x;
    const int w = tid >> 6, lane = tid & 63, l15 = lane & 15, q = lane >> 4;

    f32x4 acc[5][4];
    #pragma unroll
    for (int c5 = 0; c5 < 5; ++c5)
        #pragma unroll
        for (int nc = 0; nc < 4; ++nc) acc[c5][nc] = (f32x4)0.f;

    #pragma unroll
    for (int ks = 0; ks < 8; ++ks) {
        short8 af[5], bf[4];
        #pragma unroll
        for (int c5 = 0; c5 < 5; ++c5)
            af[c5] = *(const short8*)&Wb[(w * 80 + c5 * 16 + l15) * CC + ks * 32 + q * 8];
        #pragma unroll
        for (int nc = 0; nc < 4; ++nc)
            bf[nc] = *(const short8*)&xT[((size_t)b * NN + n0 + nc * 16 + l15) * CC + ks * 32 + q * 8];
        #pragma unroll
        for (int c5 = 0; c5 < 5; ++c5)
            #pragma unroll
            for (int nc = 0; nc < 4; ++nc)
                acc[c5][nc] = __builtin_amdgcn_mfma_f32_16x16x32_bf16(af[c5], bf[nc], acc[c5][nc], 0, 0, 0);
    }

    #pragma unroll
    for (int c5 = 0; c5 < 5; ++c5) {
        const int o0 = w * 80 + c5 * 16;
        float bia[4];
        #pragma unroll
        for (int r = 0; r < 4; ++r) bia[r] = bias[o0 + q * 4 + r];
        if (o0 >= 64) {
            #pragma unroll
            for (int nc = 0; nc < 4; ++nc)
                #pragma unroll
                for (int r = 0; r < 4; ++r)
                    V[((size_t)b * CC + o0 - 64 + q * 4 + r) * NN + n0 + nc * 16 + l15] =
                        f2bf(acc[c5][nc][r] + bia[r]);
        } else {
            ushort* dst = (o0 < 32) ? Q : Kt;
            const int oo = (o0 & 31) + q * 4;
            #pragma unroll
            for (int nc = 0; nc < 4; ++nc) {
                short4v h;
                #pragma unroll
                for (int r = 0; r < 4; ++r) h[r] = (short)f2bf(acc[c5][nc][r] + bia[r]);
                *(short4v*)&dst[((size_t)b * NN + n0 + nc * 16 + l15) * CKK + oo] = h;
            }
        }
    }
}

// ---------------- k2: flash attention, 32 rows/wave, G=2, direct-L2 K/V ----
// Op[g][b][c][n] (bf16, normalized per segment), Mp/Lp[g][b][n] (f32).
__global__ __launch_bounds__(256, 1) void attn_mfma_kernel(
    const ushort* __restrict__ Q, const ushort* __restrict__ K,
    const ushort* __restrict__ V,
    ushort* __restrict__ Op, float* __restrict__ Mp, float* __restrict__ Lp)
{
    __shared__ __align__(16) ushort pb[4][32][40];   // per-wave P tile [n][m], 2-way max
    __shared__ float alph[4][32];                    // per-wave row-broadcast

    // id -> (batch, kv-segment, row-block); XCD-pinned: batch b on XCDs {2b,2b+1}
    const int id = blockIdx.x;            // 256 blocks
    const int xcd = id & 7, ix = id >> 3;
    const int b = xcd >> 1, g = xcd & 1;
    const int n0 = ix * 128;

    const int tid = threadIdx.x;
    const int w = tid >> 6, lane = tid & 63, l15 = lane & 15, q = lane >> 4;
    const int n0w = n0 + w * 32;

    // Q fragments (A): 2 x 16 rows
    short8 qf0 = *(const short8*)&Q[((size_t)b * NN + n0w + l15) * CKK + q * 8];
    short8 qf1 = *(const short8*)&Q[((size_t)b * NN + n0w + 16 + l15) * CKK + q * 8];

    f32x4 acc[16][2];                     // O^T: D[c=ci*16+q*4+r][n=nc*16+l15]
    #pragma unroll
    for (int ci = 0; ci < 16; ++ci) { acc[ci][0] = (f32x4)0.f; acc[ci][1] = (f32x4)0.f; }
    float m_i[2][4], l_p[2][4];
    #pragma unroll
    for (int a = 0; a < 2; ++a)
        #pragma unroll
        for (int r = 0; r < 4; ++r) { m_i[a][r] = -3.0e38f; l_p[a][r] = 0.f; }

    const size_t kbase = (size_t)b * NN * CKK;
    const size_t vbase = (size_t)b * CC * NN;
    const int m_start = g * (NN / 2);

    // K prefetch for tile 0
    short8 k0 = *(const short8*)&K[kbase + (size_t)(m_start + l15) * CKK + q * 8];
    short8 k1 = *(const short8*)&K[kbase + (size_t)(m_start + 16 + l15) * CKK + q * 8];

    for (int mt = 0; mt < (NN / 2) / 32; ++mt) {
        const int m0 = m_start + mt * 32;

        // V A-frags direct from global (L2-hot, L1-dedup across waves)
        short8 vf[16];
        #pragma unroll
        for (int ci = 0; ci < 16; ++ci)
            vf[ci] = *(const short8*)&V[vbase + (size_t)(ci * 16 + l15) * NN + m0 + q * 8];

        // ---- S = Q.K^T (32 rows x 32 cols) ----
        f32x4 s00 = __builtin_amdgcn_mfma_f32_16x16x32_bf16(qf0, k0, (f32x4)0.f, 0, 0, 0);
        f32x4 s01 = __builtin_amdgcn_mfma_f32_16x16x32_bf16(qf0, k1, (f32x4)0.f, 0, 0, 0);
        f32x4 s10 = __builtin_amdgcn_mfma_f32_16x16x32_bf16(qf1, k0, (f32x4)0.f, 0, 0, 0);
        f32x4 s11 = __builtin_amdgcn_mfma_f32_16x16x32_bf16(qf1, k1, (f32x4)0.f, 0, 0, 0);

        // K prefetch for next tile
        if (mt < (NN / 2) / 32 - 1) {
            k0 = *(const short8*)&K[kbase + (size_t)(m0 + 32 + l15) * CKK + q * 8];
            k1 = *(const short8*)&K[kbase + (size_t)(m0 + 48 + l15) * CKK + q * 8];
        }

        // ---- online softmax; S rows = a*16+q*4+r, cols m = mh*16+l15 ----
        bool need = false;
        #pragma unroll
        for (int a = 0; a < 2; ++a) {
            #pragma unroll
            for (int r = 0; r < 4; ++r) {
                float sv0 = (a == 0) ? s00[r] : s10[r];
                float sv1 = (a == 0) ? s01[r] : s11[r];
                float mx = fmaxf(sv0, sv1);
                #pragma unroll
                for (int d = 1; d < 16; d <<= 1) mx = fmaxf(mx, __shfl_xor(mx, d));
                const float mo = m_i[a][r];
                const float mn = fmaxf(mo, mx);
                need = need || (mn > mo);
                const float al = __expf(mo - mn);
                const float p0 = __expf(sv0 - mn);
                const float p1 = __expf(sv1 - mn);
                l_p[a][r] = l_p[a][r] * al + p0 + p1;
                m_i[a][r] = mn;
                const int row = a * 16 + q * 4 + r;
                pb[w][row][l15]      = f2bf(p0);
                pb[w][row][16 + l15] = f2bf(p1);
                if (l15 == 0) alph[w][row] = al;
            }
        }

        // rescale acc (factor indexed by n-col = l15) via LDS broadcast
        if (__any(need)) {
            const float a0 = alph[w][l15];
            const float a1 = alph[w][16 + l15];
            #pragma unroll
            for (int ci = 0; ci < 16; ++ci) { acc[ci][0] *= a0; acc[ci][1] *= a1; }
        }

        // P B-frags: B^T[n][m] = P row-major
        short8 pB0 = *(const short8*)&pb[w][l15][q * 8];
        short8 pB1 = *(const short8*)&pb[w][16 + l15][q * 8];

        // ---- PV: O^T[c][n] += Vc[c][m] * P^T[m][n] ----
        #pragma unroll
        for (int ci = 0; ci < 16; ++ci) {
            acc[ci][0] = __builtin_amdgcn_mfma_f32_16x16x32_bf16(vf[ci], pB0, acc[ci][0], 0, 0, 0);
            acc[ci][1] = __builtin_amdgcn_mfma_f32_16x16x32_bf16(vf[ci], pB1, acc[ci][1], 0, 0, 0);
        }
    }

    // ---- epilogue: finish row-sums, write partials ----
    #pragma unroll
    for (int a = 0; a < 2; ++a) {
        #pragma unroll
        for (int r = 0; r < 4; ++r) {
            float l = l_p[a][r];
            #pragma unroll
            for (int d = 1; d < 16; d <<= 1) l += __shfl_xor(l, d);
            const int row = a * 16 + q * 4 + r;
            if (l15 == 0) {
                alph[w][row] = 1.f / l;
                const size_t nidx = (size_t)(g * BB + b) * NN + n0w + row;
                Mp[nidx] = m_i[a][r];
                Lp[nidx] = l;
            }
        }
    }
    const float inv0 = alph[w][l15];
    const float inv1 = alph[w][16 + l15];
    ushort* ob = Op + ((size_t)(g * BB + b) * CC) * NN;
    #pragma unroll
    for (int ci = 0; ci < 16; ++ci) {
        #pragma unroll
        for (int r = 0; r < 4; ++r) {
            const size_t rowoff = (size_t)(ci * 16 + q * 4 + r) * NN + n0w;
            ob[rowoff + l15]      = f2bf(acc[ci][0][r] * inv0);
            ob[rowoff + 16 + l15] = f2bf(acc[ci][1][r] * inv1);
        }
    }
}

// ---------------- k3: combine partials + residual epilogue ----------------
__global__ __launch_bounds__(256) void combine_kernel(
    const ushort* __restrict__ Op, const float* __restrict__ Mp,
    const float* __restrict__ Lp, const float* __restrict__ x,
    const float* __restrict__ gamma, float* __restrict__ out)
{
    const int b = blockIdx.z, c0 = blockIdx.y * 64;
    const int n = blockIdx.x * 256 + threadIdx.x;
    const size_t n0i = (size_t)b * NN + n;
    const size_t n1i = (size_t)(BB + b) * NN + n;
    const float m0 = Mp[n0i], m1 = Mp[n1i];
    const float l0 = Lp[n0i], l1 = Lp[n1i];
    const float M = fmaxf(m0, m1);
    const float w0 = l0 * __expf(m0 - M), w1 = l1 * __expf(m1 - M);
    const float inv = 1.f / (w0 + w1);
    const float c0f = w0 * inv, c1f = w1 * inv;
    const float gm = gamma[0];
    #pragma unroll 4
    for (int c = 0; c < 64; ++c) {
        const size_t row = (size_t)(c0 + c) * NN + n;
        const float o = c0f * bf2f(Op[(size_t)b * CC * NN + row]) +
                        c1f * bf2f(Op[(size_t)(BB + b) * CC * NN + row]);
        const size_t xo = (size_t)b * CC * NN + row;
        out[xo] = gm * o + x[xo];
    }
}

extern "C" void kernel_launch(void* const* d_in, const int* in_sizes, int n_in,
                              void* d_out, int out_size, void* d_ws, size_t ws_size,
                              hipStream_t stream) {
    const float* x     = (const float*)d_in[0];
    const float* Wq    = (const float*)d_in[1];
    const float* bq    = (const float*)d_in[2];
    const float* Wk    = (const float*)d_in[3];
    const float* bk    = (const float*)d_in[4];
    const float* Wv    = (const float*)d_in[5];
    const float* bv    = (const float*)d_in[6];
    const float* gamma = (const float*)d_in[7];
    float* out = (float*)d_out;

    char* p = (char*)d_ws;
    ushort* Wb   = (ushort*)(p);                 // 163840
    float*  bias = (float*) (p + 163840);        // 1280
    ushort* xT   = (ushort*)(p + 165120);        // 8388608
    ushort* Qb   = (ushort*)(p + 8553728);       // 1048576
    ushort* Kb   = (ushort*)(p + 9602304);       // 1048576
    ushort* Vc   = (ushort*)(p + 10650880);      // 8388608
    ushort* Opb  = (ushort*)(p + 19039488);      // 16777216 (2 segs bf16)
    float*  Mpb  = (float*) (p + 35816704);      // 131072
    float*  Lpb  = (float*) (p + 35947776);      // 131072
    // total 36,078,848 B (< 37.7MB proven in round 1)

    pack_w_kernel<<<dim3(320), 256, 0, stream>>>(Wq, bq, Wk, bk, Wv, bv, Wb, bias);
    xpose_kernel<<<dim3(NN / 32, CC / 32, BB), 256, 0, stream>>>(x, xT);
    qkv_mfma_kernel<<<dim3(NN / 64, BB), 256, 0, stream>>>(Wb, bias, xT, Qb, Kb, Vc);
    attn_mfma_kernel<<<dim3(256), 256, 0, stream>>>(Qb, Kb, Vc, Opb, Mpb, Lpb);
    combine_kernel<<<dim3(NN / 256, CC / 64, BB), 256, 0, stream>>>(Opb, Mpb, Lpb, x, gamma, out);
}